// Round 1
// baseline (669.976 us; speedup 1.0000x reference)
//
#include <hip/hip_runtime.h>
#include <math.h>

#define FSTRIDE 256   // 4 feature slices of 64 per node, k-major within row

// ---------------- utility ----------------
__global__ void zero_k(int* __restrict__ p, int n) {
    int i = blockIdx.x * blockDim.x + threadIdx.x;
    int st = gridDim.x * blockDim.x;
    for (; i < n; i += st) p[i] = 0;
}

// ---------------- CSR build ----------------
__global__ void hist_k(const int* __restrict__ dst, int* __restrict__ cnt, int E) {
    int i = blockIdx.x * blockDim.x + threadIdx.x;
    int st = gridDim.x * blockDim.x;
    for (; i < E; i += st) atomicAdd(&cnt[dst[i]], 1);
}

// per-1024-chunk sums + dinv (block = 256 threads, chunk = 1024 elems)
__global__ void degsum_k(const int* __restrict__ cnt, float* __restrict__ dinv,
                         int* __restrict__ csum, int n) {
    int base = blockIdx.x * 1024;
    int s = 0;
    for (int i = threadIdx.x; i < 1024; i += 256) {
        int idx = base + i;
        int v = (idx < n) ? cnt[idx] : 0;
        if (idx < n) dinv[idx] = 1.0f / sqrtf((float)(v > 1 ? v : 1));
        s += v;
    }
    for (int off = 32; off; off >>= 1) s += __shfl_down(s, off);
    __shared__ int ws[4];
    if ((threadIdx.x & 63) == 0) ws[threadIdx.x >> 6] = s;
    __syncthreads();
    if (threadIdx.x == 0) csum[blockIdx.x] = ws[0] + ws[1] + ws[2] + ws[3];
}

// exclusive scan of chunk sums (nb <= 256), single block of 256
__global__ void scansums_k(int* __restrict__ csum, int nb) {
    __shared__ int buf[256];
    int v = (threadIdx.x < nb) ? csum[threadIdx.x] : 0;
    buf[threadIdx.x] = v;
    __syncthreads();
    int x = v;
    for (int off = 1; off < 256; off <<= 1) {
        int t = (threadIdx.x >= off) ? buf[threadIdx.x - off] : 0;
        __syncthreads();
        x += t;
        buf[threadIdx.x] = x;
        __syncthreads();
    }
    if (threadIdx.x < nb) csum[threadIdx.x] = x - v;
}

// per-chunk exclusive scan + chunk offset -> row_ptr (block = 1024 threads)
__global__ void scanchunk_k(const int* __restrict__ cnt, const int* __restrict__ csum,
                            int* __restrict__ rowp, int n, int E) {
    __shared__ int buf[1024];
    int base = blockIdx.x * 1024;
    int idx = base + threadIdx.x;
    int v = (idx < n) ? cnt[idx] : 0;
    buf[threadIdx.x] = v;
    __syncthreads();
    int x = v;
    for (int off = 1; off < 1024; off <<= 1) {
        int t = (threadIdx.x >= off) ? buf[threadIdx.x - off] : 0;
        __syncthreads();
        x += t;
        buf[threadIdx.x] = x;
        __syncthreads();
    }
    if (idx < n) rowp[idx] = csum[blockIdx.x] + x - v;
    if (idx == 0 && blockIdx.x == 0) rowp[n] = E;
}

__global__ void fill_k(const int* __restrict__ src, const int* __restrict__ dst,
                       const int* __restrict__ rowp, int* __restrict__ fpos,
                       int* __restrict__ colb, int E) {
    int i = blockIdx.x * blockDim.x + threadIdx.x;
    int st = gridDim.x * blockDim.x;
    for (; i < E; i += st) {
        int d = dst[i];
        int p = atomicAdd(&fpos[d], 1);
        colb[rowp[d] + p] = src[i];
    }
}

// ---------------- fused 2-layer MLP: F[:,0:64] = relu(relu(x@W1+b1)@W2+b2) ----------------
__global__ __launch_bounds__(256) void mlp_k(const float* __restrict__ x,
        const float* __restrict__ W1, const float* __restrict__ b1,
        const float* __restrict__ W2, const float* __restrict__ b2,
        float* __restrict__ F, int n) {
    __shared__ float Ws1[64 * 64];
    __shared__ float Ws2[64 * 64];
    __shared__ float xs[16][64];
    __shared__ float h1s[16][64];
    int tid = threadIdx.x;
    int base = blockIdx.x * 16;
    for (int idx = tid; idx < 4096; idx += 256) { Ws1[idx] = W1[idx]; Ws2[idx] = W2[idx]; }
    for (int idx = tid; idx < 1024; idx += 256) {
        int r = idx >> 6, c = idx & 63;
        int node = base + r;
        xs[r][c] = (node < n) ? x[node * 64 + c] : 0.f;
    }
    __syncthreads();
    int lane = tid & 63, w = tid >> 6;
    int r0 = w * 4;
    float b1j = b1[lane], b2j = b2[lane];

    float a0 = b1j, a1 = b1j, a2 = b1j, a3 = b1j;
    for (int k = 0; k < 64; k += 4) {
        float w0 = Ws1[(k + 0) * 64 + lane], w1 = Ws1[(k + 1) * 64 + lane];
        float w2 = Ws1[(k + 2) * 64 + lane], w3 = Ws1[(k + 3) * 64 + lane];
        float4 xv;
        xv = *(const float4*)&xs[r0 + 0][k]; a0 += xv.x * w0 + xv.y * w1 + xv.z * w2 + xv.w * w3;
        xv = *(const float4*)&xs[r0 + 1][k]; a1 += xv.x * w0 + xv.y * w1 + xv.z * w2 + xv.w * w3;
        xv = *(const float4*)&xs[r0 + 2][k]; a2 += xv.x * w0 + xv.y * w1 + xv.z * w2 + xv.w * w3;
        xv = *(const float4*)&xs[r0 + 3][k]; a3 += xv.x * w0 + xv.y * w1 + xv.z * w2 + xv.w * w3;
    }
    // h1 rows r0..r0+3 written AND read only by this wave -> no cross-wave barrier needed
    h1s[r0 + 0][lane] = fmaxf(a0, 0.f);
    h1s[r0 + 1][lane] = fmaxf(a1, 0.f);
    h1s[r0 + 2][lane] = fmaxf(a2, 0.f);
    h1s[r0 + 3][lane] = fmaxf(a3, 0.f);

    a0 = b2j; a1 = b2j; a2 = b2j; a3 = b2j;
    for (int k = 0; k < 64; k += 4) {
        float w0 = Ws2[(k + 0) * 64 + lane], w1 = Ws2[(k + 1) * 64 + lane];
        float w2 = Ws2[(k + 2) * 64 + lane], w3 = Ws2[(k + 3) * 64 + lane];
        float4 hv;
        hv = *(const float4*)&h1s[r0 + 0][k]; a0 += hv.x * w0 + hv.y * w1 + hv.z * w2 + hv.w * w3;
        hv = *(const float4*)&h1s[r0 + 1][k]; a1 += hv.x * w0 + hv.y * w1 + hv.z * w2 + hv.w * w3;
        hv = *(const float4*)&h1s[r0 + 2][k]; a2 += hv.x * w0 + hv.y * w1 + hv.z * w2 + hv.w * w3;
        hv = *(const float4*)&h1s[r0 + 3][k]; a3 += hv.x * w0 + hv.y * w1 + hv.z * w2 + hv.w * w3;
    }
    int node = base + r0;
    if (node + 0 < n) F[(size_t)(node + 0) * FSTRIDE + lane] = fmaxf(a0, 0.f);
    if (node + 1 < n) F[(size_t)(node + 1) * FSTRIDE + lane] = fmaxf(a1, 0.f);
    if (node + 2 < n) F[(size_t)(node + 2) * FSTRIDE + lane] = fmaxf(a2, 0.f);
    if (node + 3 < n) F[(size_t)(node + 3) * FSTRIDE + lane] = fmaxf(a3, 0.f);
}

// ---------------- fold thetas into Wm1: Wm1p[k*64+h, j] = sum_c thetas[c,k]*Wm1[c*64+h, j] ----------------
__global__ void wm1p_k(const float* __restrict__ thetas, const float* __restrict__ Wm1,
                       float* __restrict__ Wm1p) {
    int idx = blockIdx.x * blockDim.x + threadIdx.x;   // 16384 total
    if (idx >= 16384) return;
    int j = idx & 63;
    int q = idx >> 6;      // k*64 + h
    int k = q >> 6;
    int hh = q & 63;
    float a = 0.f;
    for (int c = 0; c < 4; c++) a += thetas[c * 4 + k] * Wm1[(c * 64 + hh) * 64 + j];
    Wm1p[idx] = a;
}

// ---------------- propagation: F[:,k] = F[:,k-1] - dinv .* CSR_gather(F[:,k-1] .* dinv[src]) ----------------
__global__ __launch_bounds__(256) void prop_k(float* __restrict__ F,
        const int* __restrict__ rowp, const int* __restrict__ colb,
        const float* __restrict__ dinv, int n, int koff) {
    int gw = (blockIdx.x * blockDim.x + threadIdx.x) >> 6;  // one wave per node
    int lane = threadIdx.x & 63;
    if (gw >= n) return;
    int beg = rowp[gw], end = rowp[gw + 1];
    float acc = 0.f;
    int e = beg;
    for (; e + 3 < end; e += 4) {
        int s0 = colb[e], s1 = colb[e + 1], s2 = colb[e + 2], s3 = colb[e + 3];
        float d0 = dinv[s0], d1 = dinv[s1], d2 = dinv[s2], d3 = dinv[s3];
        float f0 = F[(size_t)s0 * FSTRIDE + koff + lane];
        float f1 = F[(size_t)s1 * FSTRIDE + koff + lane];
        float f2 = F[(size_t)s2 * FSTRIDE + koff + lane];
        float f3 = F[(size_t)s3 * FSTRIDE + koff + lane];
        acc += f0 * d0; acc += f1 * d1; acc += f2 * d2; acc += f3 * d3;
    }
    for (; e < end; ++e) {
        int s = colb[e];
        acc += F[(size_t)s * FSTRIDE + koff + lane] * dinv[s];
    }
    float fi = F[(size_t)gw * FSTRIDE + koff + lane];
    F[(size_t)gw * FSTRIDE + koff + 64 + lane] = fi - acc * dinv[gw];
}

// ---------------- final: out = relu(Fcat @ Wm1p + bm1) @ Wm2 + bm2 ----------------
__global__ __launch_bounds__(256) void final_k(const float* __restrict__ F,
        const float* __restrict__ Wm1p, const float* __restrict__ bm1,
        const float* __restrict__ Wm2, const float* __restrict__ bm2,
        float* __restrict__ out, int n) {
    __shared__ float Ws[16384];        // 64 KB: Wm1p [256][64]
    __shared__ float rows[4][4][256];  // 16 KB: per-wave 4 node rows
    int tid = threadIdx.x, lane = tid & 63, w = tid >> 6;
    for (int idx = tid; idx < 16384; idx += 256) Ws[idx] = Wm1p[idx];
    float bj = bm1[lane];
    float w20 = Wm2[lane * 2 + 0], w21 = Wm2[lane * 2 + 1];
    float bo0 = bm2[0], bo1 = bm2[1];
    __syncthreads();
    int ngroups = (n + 15) / 16;
    for (int g = blockIdx.x; g < ngroups; g += gridDim.x) {
        int nb = g * 16 + w * 4;
        for (int i = 0; i < 4; i++) {
            int node = nb + i;
            if (node < n) {
                float4 v = *(const float4*)&F[(size_t)node * FSTRIDE + lane * 4];
                *(float4*)&rows[w][i][lane * 4] = v;
            }
        }
        // rows[w] written/read only by wave w: in-wave LDS ordering suffices
        float a0 = bj, a1 = bj, a2 = bj, a3 = bj;
        for (int q = 0; q < 256; q += 4) {
            float w0 = Ws[(q + 0) * 64 + lane], w1 = Ws[(q + 1) * 64 + lane];
            float w2 = Ws[(q + 2) * 64 + lane], w3 = Ws[(q + 3) * 64 + lane];
            float4 r;
            r = *(const float4*)&rows[w][0][q]; a0 += r.x * w0 + r.y * w1 + r.z * w2 + r.w * w3;
            r = *(const float4*)&rows[w][1][q]; a1 += r.x * w0 + r.y * w1 + r.z * w2 + r.w * w3;
            r = *(const float4*)&rows[w][2][q]; a2 += r.x * w0 + r.y * w1 + r.z * w2 + r.w * w3;
            r = *(const float4*)&rows[w][3][q]; a3 += r.x * w0 + r.y * w1 + r.z * w2 + r.w * w3;
        }
#define EMIT(ai, ii)                                                            \
        {                                                                       \
            int node = nb + (ii);                                               \
            if (node < n) {                                                     \
                float hv = fmaxf(ai, 0.f);                                      \
                float o0 = hv * w20, o1 = hv * w21;                             \
                for (int off = 32; off; off >>= 1) {                            \
                    o0 += __shfl_down(o0, off);                                 \
                    o1 += __shfl_down(o1, off);                                 \
                }                                                               \
                if (lane == 0) { out[node * 2] = o0 + bo0; out[node * 2 + 1] = o1 + bo1; } \
            }                                                                   \
        }
        EMIT(a0, 0) EMIT(a1, 1) EMIT(a2, 2) EMIT(a3, 3)
#undef EMIT
    }
}

extern "C" void kernel_launch(void* const* d_in, const int* in_sizes, int n_in,
                              void* d_out, int out_size, void* d_ws, size_t ws_size,
                              hipStream_t stream) {
    const float* x      = (const float*)d_in[0];
    const int*   src    = (const int*)d_in[1];
    const int*   dst    = (const int*)d_in[2];
    const float* thetas = (const float*)d_in[3];
    const float* W1     = (const float*)d_in[4];
    const float* b1     = (const float*)d_in[5];
    const float* W2     = (const float*)d_in[6];
    const float* b2     = (const float*)d_in[7];
    const float* Wm1    = (const float*)d_in[8];
    const float* bm1    = (const float*)d_in[9];
    const float* Wm2    = (const float*)d_in[10];
    const float* bm2    = (const float*)d_in[11];
    float* out = (float*)d_out;

    int n = in_sizes[0] / 64;
    int E = in_sizes[1];

    // workspace layout (floats/ints, 4B each):
    float* Fbuf = (float*)d_ws;                       // n*256
    float* dinv = Fbuf + (size_t)n * FSTRIDE;         // n
    int*   cnt  = (int*)(dinv + n);                   // n+1
    int*   rowp = cnt + (n + 1);                      // n+1
    int*   fpos = rowp + (n + 1);                     // n
    int*   colb = fpos + n;                           // E
    float* Wm1p = (float*)(colb + E);                 // 16384
    int*   csum = (int*)(Wm1p + 16384);               // <=256 chunk sums

    int nchunks = (n + 1023) / 1024;

    zero_k<<<512, 256, 0, stream>>>(cnt, (n + 1) + (n + 1) + n);  // cnt, rowp, fpos contiguous
    hist_k<<<2048, 256, 0, stream>>>(dst, cnt, E);
    degsum_k<<<nchunks, 256, 0, stream>>>(cnt, dinv, csum, n);
    scansums_k<<<1, 256, 0, stream>>>(csum, nchunks);
    scanchunk_k<<<nchunks, 1024, 0, stream>>>(cnt, csum, rowp, n, E);
    fill_k<<<2048, 256, 0, stream>>>(src, dst, rowp, fpos, colb, E);

    mlp_k<<<(n + 15) / 16, 256, 0, stream>>>(x, W1, b1, W2, b2, Fbuf, n);
    wm1p_k<<<64, 256, 0, stream>>>(thetas, Wm1, Wm1p);

    for (int k = 1; k < 4; k++)
        prop_k<<<((size_t)n * 64 + 255) / 256, 256, 0, stream>>>(Fbuf, rowp, colb, dinv, n, (k - 1) * 64);

    final_k<<<512, 256, 0, stream>>>(Fbuf, Wm1p, bm1, Wm2, bm2, out, n);
}

// Round 3
// 467.448 us; speedup vs baseline: 1.4333x; 1.4333x over previous
//
#include <hip/hip_runtime.h>
#include <math.h>

#define FSTRIDE 256   // 4 feature slices of 64 per node, k-major within row

__device__ __forceinline__ void fma4(float4& a, float s, const float4& b) {
    a.x = fmaf(s, b.x, a.x);
    a.y = fmaf(s, b.y, a.y);
    a.z = fmaf(s, b.z, a.z);
    a.w = fmaf(s, b.w, a.w);
}

// ---------------- utility ----------------
__global__ void zero_k(int* __restrict__ p, int n) {
    int i = blockIdx.x * blockDim.x + threadIdx.x;
    int st = gridDim.x * blockDim.x;
    for (; i < n; i += st) p[i] = 0;
}

// ---------------- CSR build ----------------
__global__ void hist_k(const int* __restrict__ dst, int* __restrict__ cnt, int E) {
    int i = blockIdx.x * blockDim.x + threadIdx.x;
    int st = gridDim.x * blockDim.x;
    for (; i < E; i += st) atomicAdd(&cnt[dst[i]], 1);
}

// per-1024-chunk sums + dinv (block = 256 threads, chunk = 1024 elems)
__global__ void degsum_k(const int* __restrict__ cnt, float* __restrict__ dinv,
                         int* __restrict__ csum, int n) {
    int base = blockIdx.x * 1024;
    int s = 0;
    for (int i = threadIdx.x; i < 1024; i += 256) {
        int idx = base + i;
        int v = (idx < n) ? cnt[idx] : 0;
        if (idx < n) dinv[idx] = 1.0f / sqrtf((float)(v > 1 ? v : 1));
        s += v;
    }
    for (int off = 32; off; off >>= 1) s += __shfl_down(s, off);
    __shared__ int ws[4];
    if ((threadIdx.x & 63) == 0) ws[threadIdx.x >> 6] = s;
    __syncthreads();
    if (threadIdx.x == 0) csum[blockIdx.x] = ws[0] + ws[1] + ws[2] + ws[3];
}

// exclusive scan of chunk sums (nb <= 256), single block of 256
__global__ void scansums_k(int* __restrict__ csum, int nb) {
    __shared__ int buf[256];
    int v = (threadIdx.x < nb) ? csum[threadIdx.x] : 0;
    buf[threadIdx.x] = v;
    __syncthreads();
    int x = v;
    for (int off = 1; off < 256; off <<= 1) {
        int t = (threadIdx.x >= off) ? buf[threadIdx.x - off] : 0;
        __syncthreads();
        x += t;
        buf[threadIdx.x] = x;
        __syncthreads();
    }
    if (threadIdx.x < nb) csum[threadIdx.x] = x - v;
}

// per-chunk exclusive scan + chunk offset -> row_ptr (block = 1024 threads)
__global__ void scanchunk_k(const int* __restrict__ cnt, const int* __restrict__ csum,
                            int* __restrict__ rowp, int n, int E) {
    __shared__ int buf[1024];
    int base = blockIdx.x * 1024;
    int idx = base + threadIdx.x;
    int v = (idx < n) ? cnt[idx] : 0;
    buf[threadIdx.x] = v;
    __syncthreads();
    int x = v;
    for (int off = 1; off < 1024; off <<= 1) {
        int t = (threadIdx.x >= off) ? buf[threadIdx.x - off] : 0;
        __syncthreads();
        x += t;
        buf[threadIdx.x] = x;
        __syncthreads();
    }
    if (idx < n) rowp[idx] = csum[blockIdx.x] + x - v;
    if (idx == 0 && blockIdx.x == 0) rowp[n] = E;
}

__global__ void fill_k(const int* __restrict__ src, const int* __restrict__ dst,
                       const int* __restrict__ rowp, int* __restrict__ fpos,
                       int* __restrict__ colb, int E) {
    int i = blockIdx.x * blockDim.x + threadIdx.x;
    int st = gridDim.x * blockDim.x;
    for (; i < E; i += st) {
        int d = dst[i];
        int p = atomicAdd(&fpos[d], 1);
        colb[rowp[d] + p] = src[i];
    }
}

// ---------------- fused 2-layer MLP, register-tiled ----------------
// tile: 64 nodes x 64 cols, thread (ti,tj) owns 4 nodes x 4 cols
__global__ __launch_bounds__(256) void mlp_k(const float* __restrict__ x,
        const float* __restrict__ W1, const float* __restrict__ b1,
        const float* __restrict__ W2, const float* __restrict__ b2,
        float* __restrict__ F, int n, int ntiles) {
    __shared__ float Ws1[64 * 64];   // 16 KB, [k][j]
    __shared__ float Ws2[64 * 64];   // 16 KB
    __shared__ float xT[64 * 68];    // 17.4 KB, [k][node], stride 68 (16B-aligned rows)
    int tid = threadIdx.x;
    int ti = tid >> 4, tj = tid & 15;
    for (int idx = tid; idx < 4096; idx += 256) { Ws1[idx] = W1[idx]; Ws2[idx] = W2[idx]; }
    float4 b1v = *(const float4*)&b1[4 * tj];
    float4 b2v = *(const float4*)&b2[4 * tj];

    for (int g = blockIdx.x; g < ntiles; g += gridDim.x) {
        int base = g * 64;
        __syncthreads();   // xT free of previous tile's readers (also covers Ws staging on iter 0)
        // stage x transposed: xT[k][node]
        for (int it = 0; it < 4; it++) {
            int node = ti + it * 16;
            int gn = base + node;
            float4 v = make_float4(0.f, 0.f, 0.f, 0.f);
            if (gn < n) v = *(const float4*)&x[(size_t)gn * 64 + 4 * tj];
            xT[(4 * tj + 0) * 68 + node] = v.x;
            xT[(4 * tj + 1) * 68 + node] = v.y;
            xT[(4 * tj + 2) * 68 + node] = v.z;
            xT[(4 * tj + 3) * 68 + node] = v.w;
        }
        __syncthreads();

        // layer 1
        float4 a0 = b1v, a1 = b1v, a2 = b1v, a3 = b1v;
        #pragma unroll 8
        for (int k = 0; k < 64; k++) {
            float4 xv = *(const float4*)&xT[k * 68 + 4 * ti];
            float4 wv = *(const float4*)&Ws1[k * 64 + 4 * tj];
            fma4(a0, xv.x, wv); fma4(a1, xv.y, wv); fma4(a2, xv.z, wv); fma4(a3, xv.w, wv);
        }
        __syncthreads();   // all reads of xT done before overwrite
        // write h1 transposed into xT: xT[col][node]
        {
            int hb = (4 * tj) * 68 + 4 * ti;
            xT[hb + 0 * 68 + 0] = fmaxf(a0.x, 0.f);
            xT[hb + 1 * 68 + 0] = fmaxf(a0.y, 0.f);
            xT[hb + 2 * 68 + 0] = fmaxf(a0.z, 0.f);
            xT[hb + 3 * 68 + 0] = fmaxf(a0.w, 0.f);
            xT[hb + 0 * 68 + 1] = fmaxf(a1.x, 0.f);
            xT[hb + 1 * 68 + 1] = fmaxf(a1.y, 0.f);
            xT[hb + 2 * 68 + 1] = fmaxf(a1.z, 0.f);
            xT[hb + 3 * 68 + 1] = fmaxf(a1.w, 0.f);
            xT[hb + 0 * 68 + 2] = fmaxf(a2.x, 0.f);
            xT[hb + 1 * 68 + 2] = fmaxf(a2.y, 0.f);
            xT[hb + 2 * 68 + 2] = fmaxf(a2.z, 0.f);
            xT[hb + 3 * 68 + 2] = fmaxf(a2.w, 0.f);
            xT[hb + 0 * 68 + 3] = fmaxf(a3.x, 0.f);
            xT[hb + 1 * 68 + 3] = fmaxf(a3.y, 0.f);
            xT[hb + 2 * 68 + 3] = fmaxf(a3.z, 0.f);
            xT[hb + 3 * 68 + 3] = fmaxf(a3.w, 0.f);
        }
        __syncthreads();

        // layer 2
        a0 = b2v; a1 = b2v; a2 = b2v; a3 = b2v;
        #pragma unroll 8
        for (int k = 0; k < 64; k++) {
            float4 xv = *(const float4*)&xT[k * 68 + 4 * ti];
            float4 wv = *(const float4*)&Ws2[k * 64 + 4 * tj];
            fma4(a0, xv.x, wv); fma4(a1, xv.y, wv); fma4(a2, xv.z, wv); fma4(a3, xv.w, wv);
        }
        // store F[:,0:64]
        int gn0 = base + 4 * ti;
        if (gn0 + 0 < n) *(float4*)&F[(size_t)(gn0 + 0) * FSTRIDE + 4 * tj] =
            make_float4(fmaxf(a0.x,0.f), fmaxf(a0.y,0.f), fmaxf(a0.z,0.f), fmaxf(a0.w,0.f));
        if (gn0 + 1 < n) *(float4*)&F[(size_t)(gn0 + 1) * FSTRIDE + 4 * tj] =
            make_float4(fmaxf(a1.x,0.f), fmaxf(a1.y,0.f), fmaxf(a1.z,0.f), fmaxf(a1.w,0.f));
        if (gn0 + 2 < n) *(float4*)&F[(size_t)(gn0 + 2) * FSTRIDE + 4 * tj] =
            make_float4(fmaxf(a2.x,0.f), fmaxf(a2.y,0.f), fmaxf(a2.z,0.f), fmaxf(a2.w,0.f));
        if (gn0 + 3 < n) *(float4*)&F[(size_t)(gn0 + 3) * FSTRIDE + 4 * tj] =
            make_float4(fmaxf(a3.x,0.f), fmaxf(a3.y,0.f), fmaxf(a3.z,0.f), fmaxf(a3.w,0.f));
    }
}

// ---------------- fold thetas into Wm1 ----------------
__global__ void wm1p_k(const float* __restrict__ thetas, const float* __restrict__ Wm1,
                       float* __restrict__ Wm1p) {
    int idx = blockIdx.x * blockDim.x + threadIdx.x;   // 16384 total
    if (idx >= 16384) return;
    int j = idx & 63;
    int q = idx >> 6;      // k*64 + h
    int k = q >> 6;
    int hh = q & 63;
    float a = 0.f;
    for (int c = 0; c < 4; c++) a += thetas[c * 4 + k] * Wm1[(c * 64 + hh) * 64 + j];
    Wm1p[idx] = a;
}

// ---------------- propagation: Fout = Fin - dinv .* CSR_gather(Fin .* dinv[src]) ----------------
__global__ __launch_bounds__(256) void prop_k(const float* __restrict__ Fin,
        float* __restrict__ Fout,
        const int* __restrict__ rowp, const int* __restrict__ colb,
        const float* __restrict__ dinv, int n) {
    int gw = (blockIdx.x * blockDim.x + threadIdx.x) >> 6;  // one wave per node
    int lane = threadIdx.x & 63;
    if (gw >= n) return;
    int beg = rowp[gw], end = rowp[gw + 1];
    float a0 = 0.f, a1 = 0.f, a2 = 0.f, a3 = 0.f;
    int e = beg;
    for (; e + 7 < end; e += 8) {
        int s0 = colb[e],     s1 = colb[e + 1], s2 = colb[e + 2], s3 = colb[e + 3];
        int s4 = colb[e + 4], s5 = colb[e + 5], s6 = colb[e + 6], s7 = colb[e + 7];
        float f0 = Fin[(size_t)s0 * FSTRIDE + lane];
        float f1 = Fin[(size_t)s1 * FSTRIDE + lane];
        float f2 = Fin[(size_t)s2 * FSTRIDE + lane];
        float f3 = Fin[(size_t)s3 * FSTRIDE + lane];
        float f4 = Fin[(size_t)s4 * FSTRIDE + lane];
        float f5 = Fin[(size_t)s5 * FSTRIDE + lane];
        float f6 = Fin[(size_t)s6 * FSTRIDE + lane];
        float f7 = Fin[(size_t)s7 * FSTRIDE + lane];
        float d0 = dinv[s0], d1 = dinv[s1], d2 = dinv[s2], d3 = dinv[s3];
        float d4 = dinv[s4], d5 = dinv[s5], d6 = dinv[s6], d7 = dinv[s7];
        a0 += f0 * d0; a1 += f1 * d1; a2 += f2 * d2; a3 += f3 * d3;
        a0 += f4 * d4; a1 += f5 * d5; a2 += f6 * d6; a3 += f7 * d7;
    }
    for (; e + 3 < end; e += 4) {
        int s0 = colb[e], s1 = colb[e + 1], s2 = colb[e + 2], s3 = colb[e + 3];
        a0 += Fin[(size_t)s0 * FSTRIDE + lane] * dinv[s0];
        a1 += Fin[(size_t)s1 * FSTRIDE + lane] * dinv[s1];
        a2 += Fin[(size_t)s2 * FSTRIDE + lane] * dinv[s2];
        a3 += Fin[(size_t)s3 * FSTRIDE + lane] * dinv[s3];
    }
    for (; e < end; ++e) {
        int s = colb[e];
        a0 += Fin[(size_t)s * FSTRIDE + lane] * dinv[s];
    }
    float acc = (a0 + a1) + (a2 + a3);
    float fi = Fin[(size_t)gw * FSTRIDE + lane];
    Fout[(size_t)gw * FSTRIDE + lane] = fi - acc * dinv[gw];
}

// ---------------- final: out = relu(Fcat @ Wm1p + bm1) @ Wm2 + bm2 ----------------
// tile: 64 nodes x 64 cols, thread (ti,tj) owns 4 nodes x 4 cols; F streamed from global
__global__ __launch_bounds__(256) void final_k(const float* __restrict__ F,
        const float* __restrict__ Wm1p, const float* __restrict__ bm1,
        const float* __restrict__ Wm2, const float* __restrict__ bm2,
        float* __restrict__ out, int n, int ntiles) {
    __shared__ float Ws[256 * 64];   // 64 KB, [k][j]
    int tid = threadIdx.x;
    int ti = tid >> 4, tj = tid & 15;
    for (int idx = tid; idx < 16384; idx += 256) Ws[idx] = Wm1p[idx];
    float4 bv = *(const float4*)&bm1[4 * tj];
    float2 w2a = ((const float2*)Wm2)[4 * tj + 0];
    float2 w2b = ((const float2*)Wm2)[4 * tj + 1];
    float2 w2c = ((const float2*)Wm2)[4 * tj + 2];
    float2 w2d = ((const float2*)Wm2)[4 * tj + 3];
    float bo0 = bm2[0], bo1 = bm2[1];
    __syncthreads();

    for (int g = blockIdx.x; g < ntiles; g += gridDim.x) {
        int base = g * 64;
        const float* fr = &F[(size_t)(base + 4 * ti) * FSTRIDE];   // rows padded to tile multiple
        float4 a0 = bv, a1 = bv, a2 = bv, a3 = bv;
        #pragma unroll 4
        for (int k = 0; k < 256; k += 4) {
            float4 w0 = *(const float4*)&Ws[(k + 0) * 64 + 4 * tj];
            float4 w1 = *(const float4*)&Ws[(k + 1) * 64 + 4 * tj];
            float4 w2 = *(const float4*)&Ws[(k + 2) * 64 + 4 * tj];
            float4 w3 = *(const float4*)&Ws[(k + 3) * 64 + 4 * tj];
            float4 r;
            r = *(const float4*)&fr[k];
            fma4(a0, r.x, w0); fma4(a0, r.y, w1); fma4(a0, r.z, w2); fma4(a0, r.w, w3);
            r = *(const float4*)&fr[FSTRIDE + k];
            fma4(a1, r.x, w0); fma4(a1, r.y, w1); fma4(a1, r.z, w2); fma4(a1, r.w, w3);
            r = *(const float4*)&fr[2 * FSTRIDE + k];
            fma4(a2, r.x, w0); fma4(a2, r.y, w1); fma4(a2, r.z, w2); fma4(a2, r.w, w3);
            r = *(const float4*)&fr[3 * FSTRIDE + k];
            fma4(a3, r.x, w0); fma4(a3, r.y, w1); fma4(a3, r.z, w2); fma4(a3, r.w, w3);
        }
#define EMIT(ai, ii)                                                             \
        {                                                                        \
            float o0 = fmaxf(ai.x,0.f)*w2a.x + fmaxf(ai.y,0.f)*w2b.x             \
                     + fmaxf(ai.z,0.f)*w2c.x + fmaxf(ai.w,0.f)*w2d.x;            \
            float o1 = fmaxf(ai.x,0.f)*w2a.y + fmaxf(ai.y,0.f)*w2b.y             \
                     + fmaxf(ai.z,0.f)*w2c.y + fmaxf(ai.w,0.f)*w2d.y;            \
            o0 += __shfl_xor(o0, 1); o1 += __shfl_xor(o1, 1);                    \
            o0 += __shfl_xor(o0, 2); o1 += __shfl_xor(o1, 2);                    \
            o0 += __shfl_xor(o0, 4); o1 += __shfl_xor(o1, 4);                    \
            o0 += __shfl_xor(o0, 8); o1 += __shfl_xor(o1, 8);                    \
            int node = base + 4 * ti + (ii);                                     \
            if (tj == 0 && node < n) { out[node * 2] = o0 + bo0;                 \
                                       out[node * 2 + 1] = o1 + bo1; }           \
        }
        EMIT(a0, 0) EMIT(a1, 1) EMIT(a2, 2) EMIT(a3, 3)
#undef EMIT
    }
}

extern "C" void kernel_launch(void* const* d_in, const int* in_sizes, int n_in,
                              void* d_out, int out_size, void* d_ws, size_t ws_size,
                              hipStream_t stream) {
    const float* x      = (const float*)d_in[0];
    const int*   src    = (const int*)d_in[1];
    const int*   dst    = (const int*)d_in[2];
    const float* thetas = (const float*)d_in[3];
    const float* W1     = (const float*)d_in[4];
    const float* b1     = (const float*)d_in[5];
    const float* W2     = (const float*)d_in[6];
    const float* b2     = (const float*)d_in[7];
    const float* Wm1    = (const float*)d_in[8];
    const float* bm1    = (const float*)d_in[9];
    const float* Wm2    = (const float*)d_in[10];
    const float* bm2    = (const float*)d_in[11];
    float* out = (float*)d_out;

    int n = in_sizes[0] / 64;
    int E = in_sizes[1];
    int ntiles = (n + 63) / 64;
    int nn = ntiles * 64;            // F padded to tile multiple (tail rows read, never kept)

    // workspace layout (floats/ints, 4B each):
    float* Fbuf = (float*)d_ws;                       // nn*256
    float* dinv = Fbuf + (size_t)nn * FSTRIDE;        // n
    int*   cnt  = (int*)(dinv + n);                   // n+1
    int*   rowp = cnt + (n + 1);                      // n+1
    int*   fpos = rowp + (n + 1);                     // n
    int*   colb = fpos + n;                           // E
    float* Wm1p = (float*)(colb + E);                 // 16384
    int*   csum = (int*)(Wm1p + 16384);               // <=256 chunk sums

    int nchunks = (n + 1023) / 1024;

    zero_k<<<512, 256, 0, stream>>>(cnt, (n + 1) + (n + 1) + n);  // cnt, rowp, fpos contiguous
    hist_k<<<2048, 256, 0, stream>>>(dst, cnt, E);
    degsum_k<<<nchunks, 256, 0, stream>>>(cnt, dinv, csum, n);
    scansums_k<<<1, 256, 0, stream>>>(csum, nchunks);
    scanchunk_k<<<nchunks, 1024, 0, stream>>>(cnt, csum, rowp, n, E);
    fill_k<<<2048, 256, 0, stream>>>(src, dst, rowp, fpos, colb, E);

    mlp_k<<<768, 256, 0, stream>>>(x, W1, b1, W2, b2, Fbuf, n, ntiles);
    wm1p_k<<<64, 256, 0, stream>>>(thetas, Wm1, Wm1p);

    for (int k = 1; k < 4; k++)
        prop_k<<<((size_t)n * 64 + 255) / 256, 256, 0, stream>>>(
            Fbuf + (k - 1) * 64, Fbuf + k * 64, rowp, colb, dinv, n);

    final_k<<<512, 256, 0, stream>>>(Fbuf, Wm1p, bm1, Wm2, bm2, out, n, ntiles);
}